// Round 8
// baseline (492.329 us; speedup 1.0000x reference)
//
#include <hip/hip_runtime.h>
#include <stdint.h>

#define NTHREADS 256
#define KTOP 50
#define CAP 1024
#define EPSV 1e-8f
#define MAXGRP 32

typedef unsigned long long u64;
typedef uint32_t u32;

// s_c: 0=cntP 1=cntQ 2=ovfl 3=fallback counter
#define C_CNTP 0
#define C_CNTQ 1
#define C_OVF  2
#define C_GEN  3

// ---- block-wide float max ----
__device__ __forceinline__ float block_max(float v, float* s_f, int tid) {
    for (int off = 32; off; off >>= 1) v = fmaxf(v, __shfl_down(v, off));
    if ((tid & 63) == 0) s_f[tid >> 6] = v;
    __syncthreads();
    if (tid == 0) {
        float m = s_f[0];
        for (int w = 1; w < NTHREADS / 64; ++w) m = fmaxf(m, s_f[w]);
        s_f[4] = m;
    }
    __syncthreads();
    float r = s_f[4];
    __syncthreads();
    return r;
}

// ---- u32-key push: key = (bits(v)-bits(t))<<16 | (0xFFFF-idx) ----
__device__ __forceinline__ void push32(u32* cand, u32* cnt, u32* ovf,
                                       float v, int idx, float t, u32 tbits) {
    if (v >= t) {
        u32 delta = __float_as_uint(v) - tbits;
        if (delta > 0xFFFFu) { *ovf = 1u; delta = 0xFFFFu; }
        u32 pos = atomicAdd(cnt, 1u);
        if (pos < CAP) cand[pos] = (delta << 16) | (0xFFFFu - (u32)idx);
    }
}

// ---- u64 push (validated fallback path) ----
__device__ __forceinline__ void push64(u64* cand, u32* cnt,
                                       float v, int idx, float t) {
    if (v >= t) {
        u32 pos = atomicAdd(cnt, 1u);
        if (pos < CAP)
            cand[pos] = (((u64)__float_as_uint(v)) << 16) |
                        (u64)(0xFFFFu - (u32)idx);
    }
}

// ---- cold path: per-element direct u64 collect (validated R2-R6) ----
__device__ int collect_direct64(const float* __restrict__ row, int V, float t,
                                u64* cand, u32* s_cnt, int tid) {
    if (tid == 0) *s_cnt = 0;
    __syncthreads();
    int mis = (int)(((uintptr_t)row >> 2) & 3);
    int head = (4 - mis) & 3; if (head > V) head = V;
    if (tid < head) push64(cand, s_cnt, row[tid], tid, t);
    int nvec = (V - head) >> 2;
    const float4* vr = reinterpret_cast<const float4*>(row + head);
    for (int i = tid; i < nvec; i += NTHREADS) {
        float4 v = vr[i];
        int b = head + (i << 2);
        push64(cand, s_cnt, v.x, b, t);     push64(cand, s_cnt, v.y, b + 1, t);
        push64(cand, s_cnt, v.z, b + 2, t); push64(cand, s_cnt, v.w, b + 3, t);
    }
    for (int i = head + (nvec << 2) + tid; i < V; i += NTHREADS)
        push64(cand, s_cnt, row[i], i, t);
    __syncthreads();
    int n = (int)*s_cnt;
    __syncthreads();
    return n;
}

// ---- u64 two-phase find_topk (validated R4-R6 fallback) ----
__device__ void find_topk64(const u64* cand, int nc, uint16_t* top,
                            u64* s_merge, int tid) {
    int lane = tid & 63, w = tid >> 6;
    u64 r0 = 0, r1 = 0, r2 = 0, r3 = 0;
    int j0 = (w << 6) + lane;
    if (j0 < nc)       r0 = cand[j0];
    if (j0 + 256 < nc) r1 = cand[j0 + 256];
    if (j0 + 512 < nc) r2 = cand[j0 + 512];
    if (j0 + 768 < nc) r3 = cand[j0 + 768];
    for (int k = 0; k < KTOP; ++k) {
        u64 a = r0 > r1 ? r0 : r1;
        u64 b = r2 > r3 ? r2 : r3;
        u64 m = a > b ? a : b;
        #pragma unroll
        for (int off = 32; off; off >>= 1) {
            u64 o = __shfl_xor(m, off);
            if (o > m) m = o;
        }
        if (lane == 0) s_merge[w * KTOP + k] = m;
        if (r0 == m) r0 = 0; else if (r1 == m) r1 = 0;
        else if (r2 == m) r2 = 0; else if (r3 == m) r3 = 0;
    }
    __syncthreads();
    if (w == 0) {
        u64 q0 = 0, q1 = 0, q2 = 0, q3 = 0;
        if (lane < 4 * KTOP)       q0 = s_merge[lane];
        if (lane + 64 < 4 * KTOP)  q1 = s_merge[lane + 64];
        if (lane + 128 < 4 * KTOP) q2 = s_merge[lane + 128];
        if (lane + 192 < 4 * KTOP) q3 = s_merge[lane + 192];
        for (int k = 0; k < KTOP; ++k) {
            u64 a = q0 > q1 ? q0 : q1;
            u64 b = q2 > q3 ? q2 : q3;
            u64 m = a > b ? a : b;
            #pragma unroll
            for (int off = 32; off; off >>= 1) {
                u64 o = __shfl_xor(m, off);
                if (o > m) m = o;
            }
            if (lane == 0) top[k] = (uint16_t)(0xFFFFu - (u32)(m & 0xFFFFu));
            if (q0 == m) q0 = 0; else if (q1 == m) q1 = 0;
            else if (q2 == m) q2 = 0; else if (q3 == m) q3 = 0;
        }
    }
    __syncthreads();
}

// ---- single-wave u32 top-50: NR regs/lane, zero barriers, non-destructive LDS
template <int NR>
__device__ void find32(const u32* cand, int nc, uint16_t* top, int lane) {
    u32 r[NR];
    #pragma unroll
    for (int j = 0; j < NR; ++j) {
        int idx = lane + j * 64;
        r[j] = (idx < nc) ? cand[idx] : 0u;
    }
    u32 mine = 0;
    for (int k = 0; k < KTOP; ++k) {
        u32 m = 0;
        #pragma unroll
        for (int j = 0; j < NR; ++j) m = r[j] > m ? r[j] : m;
        #pragma unroll
        for (int off = 32; off; off >>= 1) {
            u32 o = __shfl_xor(m, off);
            m = o > m ? o : m;
        }
        if (lane == k) mine = m;
        #pragma unroll
        for (int j = 0; j < NR; ++j) if (r[j] == m) r[j] = 0;
    }
    if (lane < KTOP) top[lane] = (uint16_t)(0xFFFFu - (mine & 0xFFFFu));
}

__device__ __forceinline__ float max16(float4 a, float4 b, float4 c, float4 d) {
    float m0 = fmaxf(fmaxf(a.x, a.y), fmaxf(a.z, a.w));
    float m1 = fmaxf(fmaxf(b.x, b.y), fmaxf(b.z, b.w));
    float m2 = fmaxf(fmaxf(c.x, c.y), fmaxf(c.z, c.w));
    float m3 = fmaxf(fmaxf(d.x, d.y), fmaxf(d.z, d.w));
    return fmaxf(fmaxf(m0, m1), fmaxf(m2, m3));
}

#define PER4 (4 * NTHREADS)

#define LOADG(P0,P1,P2,P3,Q0,Q1,Q2,Q3,g) do { int _o = (g) * PER4 + tid; \
    P0 = vp[_o]; P1 = vp[_o + NTHREADS]; P2 = vp[_o + 2*NTHREADS]; P3 = vp[_o + 3*NTHREADS]; \
    Q0 = vq[_o]; Q1 = vq[_o + NTHREADS]; Q2 = vq[_o + 2*NTHREADS]; Q3 = vq[_o + 3*NTHREADS]; } while (0)

#define CONSUME(P0,P1,P2,P3,Q0,Q1,Q2,Q3,g) do { \
    float _mp = max16(P0,P1,P2,P3); float _mq = max16(Q0,Q1,Q2,Q3); \
    maskP |= (_mp >= tP) ? (1u << (g)) : 0u; \
    maskQ |= (_mq >= tQ) ? (1u << (g)) : 0u; } while (0)

#define SCHED_HINT() do { \
    __builtin_amdgcn_sched_group_barrier(0x020, 8, 0); \
    __builtin_amdgcn_sched_group_barrier(0x002, 60, 0); \
    __builtin_amdgcn_sched_group_barrier(0x020, 8, 0); \
    __builtin_amdgcn_sched_group_barrier(0x002, 60, 0); } while (0)

__global__ __launch_bounds__(NTHREADS, 4)
void topk_jsd_kernel(const float* __restrict__ p, const float* __restrict__ q,
                     float* __restrict__ out, int V)
{
    __shared__ u64 candRaw[CAP];                 // u32 views: P = lo 4KB, Q = hi 4KB
    __shared__ u64 s_merge[4 * KTOP];
    __shared__ float s_f[8];
    __shared__ u32 s_c[4];
    __shared__ uint16_t topP[KTOP];
    __shared__ uint16_t topQ[KTOP];
    __shared__ uint16_t s_union[2 * KTOP];
    __shared__ int s_nu;

    u32* candP = (u32*)candRaw;
    u32* candQ = ((u32*)candRaw) + CAP;

    const int row = blockIdx.x;
    const int tid = threadIdx.x;
    const int lane = tid & 63, w = tid >> 6;
    const float* prow = p + (size_t)row * (size_t)V;
    const float* qrow = q + (size_t)row * (size_t)V;

    // ---- sample phase: max of first 2048 elems ----
    int smp = V < 2048 ? V : 2048;
    float msP = 0.f, msQ = 0.f;
    for (int i = tid; i < smp; i += NTHREADS) {
        msP = fmaxf(msP, prow[i]);
        msQ = fmaxf(msQ, qrow[i]);
    }
    float MsP = block_max(msP, s_f, tid);
    float MsQ = block_max(msQ, s_f, tid);

    float eps0 = fminf(128.f / (float)V + 1.f / (float)smp, 0.5f);
    float tP = MsP * (1.f - eps0);
    float tQ = MsQ * (1.f - eps0);
    u32 tPb = __float_as_uint(tP), tQb = __float_as_uint(tQ);

    int misP = (int)(((uintptr_t)prow >> 2) & 3);
    int misQ = (int)(((uintptr_t)qrow >> 2) & 3);
    int headP = (4 - misP) & 3; if (headP > V) headP = V;
    int headQ = (4 - misQ) & 3; if (headQ > V) headQ = V;
    bool fast = (headP == headQ);

    int ncP = -1, ncQ = -1;
    u32 ovf = 1;

    if (fast) {
        int head = headP;
        if (tid == 0) { s_c[0] = 0; s_c[1] = 0; s_c[2] = 0; }
        __syncthreads();
        int nvec = (V - head) >> 2;
        const float4* vp = reinterpret_cast<const float4*>(prow + head);
        const float4* vq = reinterpret_cast<const float4*>(qrow + head);
        int ngrp_full = nvec / PER4;
        int ngrp = ngrp_full < MAXGRP ? ngrp_full : MAXGRP;

        u32 maskP = 0, maskQ = 0;
        float4 pa0, pa1, pa2, pa3, qa0, qa1, qa2, qa3;
        float4 pb0, pb1, pb2, pb3, qb0, qb1, qb2, qb3;

        int g = 0;
        if (ngrp > 0) LOADG(pa0,pa1,pa2,pa3,qa0,qa1,qa2,qa3, 0);
        // branchless double-buffered stream: loads for g+1/g+2 in flight
        // while consuming g/g+1 -> 8-16 outstanding loads per wave
        for (; g + 2 < ngrp; g += 2) {
            LOADG(pb0,pb1,pb2,pb3,qb0,qb1,qb2,qb3, g + 1);
            CONSUME(pa0,pa1,pa2,pa3,qa0,qa1,qa2,qa3, g);
            LOADG(pa0,pa1,pa2,pa3,qa0,qa1,qa2,qa3, g + 2);
            CONSUME(pb0,pb1,pb2,pb3,qb0,qb1,qb2,qb3, g + 1);
            SCHED_HINT();
        }
        if (ngrp - g == 2) {
            LOADG(pb0,pb1,pb2,pb3,qb0,qb1,qb2,qb3, g + 1);
            CONSUME(pa0,pa1,pa2,pa3,qa0,qa1,qa2,qa3, g);
            CONSUME(pb0,pb1,pb2,pb3,qb0,qb1,qb2,qb3, g + 1);
        } else if (ngrp - g == 1) {
            CONSUME(pa0,pa1,pa2,pa3,qa0,qa1,qa2,qa3, g);
        }

        // head elements
        if (tid < head) {
            push32(candP, &s_c[C_CNTP], &s_c[C_OVF], prow[tid], tid, tP, tPb);
            push32(candQ, &s_c[C_CNTQ], &s_c[C_OVF], qrow[tid], tid, tQ, tQb);
        }
        // remainder float4s + scalar tail (per-element, post-hot-loop)
        for (int i = ngrp * PER4 + tid; i < nvec; i += NTHREADS) {
            float4 a = vp[i], b = vq[i];
            int e = head + (i << 2);
            push32(candP, &s_c[C_CNTP], &s_c[C_OVF], a.x, e,     tP, tPb);
            push32(candP, &s_c[C_CNTP], &s_c[C_OVF], a.y, e + 1, tP, tPb);
            push32(candP, &s_c[C_CNTP], &s_c[C_OVF], a.z, e + 2, tP, tPb);
            push32(candP, &s_c[C_CNTP], &s_c[C_OVF], a.w, e + 3, tP, tPb);
            push32(candQ, &s_c[C_CNTQ], &s_c[C_OVF], b.x, e,     tQ, tQb);
            push32(candQ, &s_c[C_CNTQ], &s_c[C_OVF], b.y, e + 1, tQ, tQb);
            push32(candQ, &s_c[C_CNTQ], &s_c[C_OVF], b.z, e + 2, tQ, tQb);
            push32(candQ, &s_c[C_CNTQ], &s_c[C_OVF], b.w, e + 3, tQ, tQb);
        }
        for (int i = head + (nvec << 2) + tid; i < V; i += NTHREADS) {
            push32(candP, &s_c[C_CNTP], &s_c[C_OVF], prow[i], i, tP, tPb);
            push32(candQ, &s_c[C_CNTQ], &s_c[C_OVF], qrow[i], i, tQ, tQb);
        }
        // expansion: re-read hit groups (L2-warm) from the bitmasks
        while (maskP) {
            int gb = __ffs(maskP) - 1; maskP &= maskP - 1;
            int o = gb * PER4 + tid;
            #pragma unroll
            for (int j = 0; j < 4; ++j) {
                float4 v = vp[o + j * NTHREADS];
                int e = head + ((o + j * NTHREADS) << 2);
                push32(candP, &s_c[C_CNTP], &s_c[C_OVF], v.x, e,     tP, tPb);
                push32(candP, &s_c[C_CNTP], &s_c[C_OVF], v.y, e + 1, tP, tPb);
                push32(candP, &s_c[C_CNTP], &s_c[C_OVF], v.z, e + 2, tP, tPb);
                push32(candP, &s_c[C_CNTP], &s_c[C_OVF], v.w, e + 3, tP, tPb);
            }
        }
        while (maskQ) {
            int gb = __ffs(maskQ) - 1; maskQ &= maskQ - 1;
            int o = gb * PER4 + tid;
            #pragma unroll
            for (int j = 0; j < 4; ++j) {
                float4 v = vq[o + j * NTHREADS];
                int e = head + ((o + j * NTHREADS) << 2);
                push32(candQ, &s_c[C_CNTQ], &s_c[C_OVF], v.x, e,     tQ, tQb);
                push32(candQ, &s_c[C_CNTQ], &s_c[C_OVF], v.y, e + 1, tQ, tQb);
                push32(candQ, &s_c[C_CNTQ], &s_c[C_OVF], v.z, e + 2, tQ, tQb);
                push32(candQ, &s_c[C_CNTQ], &s_c[C_OVF], v.w, e + 3, tQ, tQb);
            }
        }
        __syncthreads();
        ncP = (int)s_c[C_CNTP];
        ncQ = (int)s_c[C_CNTQ];
        ovf = s_c[C_OVF];
        __syncthreads();
    }

    bool okP = fast && !ovf && ncP >= KTOP && ncP <= CAP;
    bool okQ = fast && !ovf && ncQ >= KTOP && ncQ <= CAP;

    // parallel single-wave extraction (non-destructive reads of cand LDS)
    if (okP && w == 0) {
        if (ncP <= 256) find32<4>(candP, ncP, topP, lane);
        else            find32<16>(candP, ncP, topP, lane);
    }
    if (okQ && w == 1) {
        if (ncQ <= 256) find32<4>(candQ, ncQ, topQ, lane);
        else            find32<16>(candQ, ncQ, topQ, lane);
    }

    // u64 fallback (validated path; overwrites candRaw)
    if (!okP) {
        float eps = eps0;
        int nc = collect_direct64(prow, V, MsP * (1.f - eps), candRaw, &s_c[C_GEN], tid);
        for (int a = 0; a < 10 && (nc < KTOP || nc > CAP); ++a) {
            eps = (nc > CAP) ? eps * 0.25f : fminf(eps * 4.f, 1.f);
            nc = collect_direct64(prow, V, MsP * (1.f - eps), candRaw, &s_c[C_GEN], tid);
        }
        if (nc > CAP) nc = CAP;
        find_topk64(candRaw, nc, topP, s_merge, tid);
    }
    if (!okQ) {
        float eps = eps0;
        int nc = collect_direct64(qrow, V, MsQ * (1.f - eps), candRaw, &s_c[C_GEN], tid);
        for (int a = 0; a < 10 && (nc < KTOP || nc > CAP); ++a) {
            eps = (nc > CAP) ? eps * 0.25f : fminf(eps * 4.f, 1.f);
            nc = collect_direct64(qrow, V, MsQ * (1.f - eps), candRaw, &s_c[C_GEN], tid);
        }
        if (nc > CAP) nc = CAP;
        find_topk64(candRaw, nc, topQ, s_merge, tid);
    }
    __syncthreads();

    // ---- union of index sets (wave 0) ----
    if (tid < KTOP) s_union[tid] = topP[tid];
    __syncthreads();
    if (tid < 64) {
        bool freshb = false; uint16_t qi = 0;
        if (tid < KTOP) {
            qi = topQ[tid]; freshb = true;
            for (int j = 0; j < KTOP; ++j) if (topP[j] == qi) freshb = false;
        }
        u64 mb = __ballot(freshb);
        int pos = __popcll(mb & ((1ull << tid) - 1ull));
        if (freshb) s_union[KTOP + pos] = qi;
        if (tid == 0) s_nu = KTOP + __popcll(mb);
    }
    __syncthreads();
    int nu = s_nu;

    // ---- gather union values (index clamp guards pathological fallbacks) ----
    float pv = 0.f, qv = 0.f;
    if (tid < nu) {
        int ui = s_union[tid]; ui = ui < V ? ui : V - 1;
        pv = prow[ui];
        qv = qrow[ui];
    }

    // ---- block-reduce masked sums ----
    float sp = pv, sq = qv;
    for (int off = 32; off; off >>= 1) { sp += __shfl_down(sp, off); sq += __shfl_down(sq, off); }
    if ((tid & 63) == 0) { s_f[w] = sp; s_f[4 + w] = sq; }
    __syncthreads();
    if (tid == 0) {
        float a = 0.f, b = 0.f;
        for (int ww = 0; ww < NTHREADS / 64; ++ww) { a += s_f[ww]; b += s_f[4 + ww]; }
        s_f[0] = a; s_f[4] = b;
    }
    __syncthreads();
    float sump = s_f[0], sumq = s_f[4];
    __syncthreads();

    // ---- JSD over union (identical formula to validated kernels) ----
    float term = 0.f;
    if (tid < nu) {
        float pn = pv / (sump + EPSV);
        float qn = qv / (sumq + EPSV);
        float mn = 0.5f * (pn + qn);
        float ps = pn + EPSV, qs = qn + EPSV, ms = mn + EPSV;
        term = 0.5f * (ps * logf(ps / ms) + qs * logf(qs / ms));
    }
    for (int off = 32; off; off >>= 1) term += __shfl_down(term, off);
    if ((tid & 63) == 0) s_f[w] = term;
    __syncthreads();
    if (tid == 0) {
        float a = 0.f;
        for (int ww = 0; ww < NTHREADS / 64; ++ww) a += s_f[ww];
        out[row] = a;
    }
}

extern "C" void kernel_launch(void* const* d_in, const int* in_sizes, int n_in,
                              void* d_out, int out_size, void* d_ws, size_t ws_size,
                              hipStream_t stream) {
    const float* p = (const float*)d_in[0];
    const float* q = (const float*)d_in[1];
    float* out = (float*)d_out;
    if (out_size <= 0) return;
    int N = out_size;            // B*S rows
    int V = in_sizes[0] / N;     // vocab size
    topk_jsd_kernel<<<dim3(N), dim3(NTHREADS), 0, stream>>>(p, q, out, V);
}

// Round 9
// 399.775 us; speedup vs baseline: 1.2315x; 1.2315x over previous
//
#include <hip/hip_runtime.h>
#include <stdint.h>

#define NTHREADS 256
#define KTOP 50
#define CAP 1024
#define EPSV 1e-8f

typedef unsigned long long u64;
typedef uint32_t u32;
typedef float __attribute__((ext_vector_type(4))) f4;

// s_c: 0=cntP 1=cntQ 2=ovfl 3=fallback counter
#define C_CNTP 0
#define C_CNTQ 1
#define C_OVF  2
#define C_GEN  3

// ---- block-wide float max ----
__device__ __forceinline__ float block_max(float v, float* s_f, int tid) {
    for (int off = 32; off; off >>= 1) v = fmaxf(v, __shfl_down(v, off));
    if ((tid & 63) == 0) s_f[tid >> 6] = v;
    __syncthreads();
    if (tid == 0) {
        float m = s_f[0];
        for (int w = 1; w < NTHREADS / 64; ++w) m = fmaxf(m, s_f[w]);
        s_f[4] = m;
    }
    __syncthreads();
    float r = s_f[4];
    __syncthreads();
    return r;
}

// ---- u32-key push: key = (bits(v)-bits(t))<<16 | (0xFFFF-idx) ----
__device__ __forceinline__ void push32(u32* cand, u32* cnt, u32* ovf,
                                       float v, int idx, float t, u32 tbits) {
    if (v >= t) {
        u32 delta = __float_as_uint(v) - tbits;
        if (delta > 0xFFFFu) { *ovf = 1u; delta = 0xFFFFu; }
        u32 pos = atomicAdd(cnt, 1u);
        if (pos < CAP) cand[pos] = (delta << 16) | (0xFFFFu - (u32)idx);
    }
}

// ---- u64 push (validated fallback path) ----
__device__ __forceinline__ void push64(u64* cand, u32* cnt,
                                       float v, int idx, float t) {
    if (v >= t) {
        u32 pos = atomicAdd(cnt, 1u);
        if (pos < CAP)
            cand[pos] = (((u64)__float_as_uint(v)) << 16) |
                        (u64)(0xFFFFu - (u32)idx);
    }
}

// ---- cold path: per-element direct u64 collect (validated R2-R8) ----
__device__ int collect_direct64(const float* __restrict__ row, int V, float t,
                                u64* cand, u32* s_cnt, int tid) {
    if (tid == 0) *s_cnt = 0;
    __syncthreads();
    int mis = (int)(((uintptr_t)row >> 2) & 3);
    int head = (4 - mis) & 3; if (head > V) head = V;
    if (tid < head) push64(cand, s_cnt, row[tid], tid, t);
    int nvec = (V - head) >> 2;
    const float4* vr = reinterpret_cast<const float4*>(row + head);
    for (int i = tid; i < nvec; i += NTHREADS) {
        float4 v = vr[i];
        int b = head + (i << 2);
        push64(cand, s_cnt, v.x, b, t);     push64(cand, s_cnt, v.y, b + 1, t);
        push64(cand, s_cnt, v.z, b + 2, t); push64(cand, s_cnt, v.w, b + 3, t);
    }
    for (int i = head + (nvec << 2) + tid; i < V; i += NTHREADS)
        push64(cand, s_cnt, row[i], i, t);
    __syncthreads();
    int n = (int)*s_cnt;
    __syncthreads();
    return n;
}

// ---- u64 two-phase find_topk (validated fallback) ----
__device__ void find_topk64(const u64* cand, int nc, uint16_t* top,
                            u64* s_merge, int tid) {
    int lane = tid & 63, w = tid >> 6;
    u64 r0 = 0, r1 = 0, r2 = 0, r3 = 0;
    int j0 = (w << 6) + lane;
    if (j0 < nc)       r0 = cand[j0];
    if (j0 + 256 < nc) r1 = cand[j0 + 256];
    if (j0 + 512 < nc) r2 = cand[j0 + 512];
    if (j0 + 768 < nc) r3 = cand[j0 + 768];
    for (int k = 0; k < KTOP; ++k) {
        u64 a = r0 > r1 ? r0 : r1;
        u64 b = r2 > r3 ? r2 : r3;
        u64 m = a > b ? a : b;
        #pragma unroll
        for (int off = 32; off; off >>= 1) {
            u64 o = __shfl_xor(m, off);
            if (o > m) m = o;
        }
        if (lane == 0) s_merge[w * KTOP + k] = m;
        if (r0 == m) r0 = 0; else if (r1 == m) r1 = 0;
        else if (r2 == m) r2 = 0; else if (r3 == m) r3 = 0;
    }
    __syncthreads();
    if (w == 0) {
        u64 q0 = 0, q1 = 0, q2 = 0, q3 = 0;
        if (lane < 4 * KTOP)       q0 = s_merge[lane];
        if (lane + 64 < 4 * KTOP)  q1 = s_merge[lane + 64];
        if (lane + 128 < 4 * KTOP) q2 = s_merge[lane + 128];
        if (lane + 192 < 4 * KTOP) q3 = s_merge[lane + 192];
        for (int k = 0; k < KTOP; ++k) {
            u64 a = q0 > q1 ? q0 : q1;
            u64 b = q2 > q3 ? q2 : q3;
            u64 m = a > b ? a : b;
            #pragma unroll
            for (int off = 32; off; off >>= 1) {
                u64 o = __shfl_xor(m, off);
                if (o > m) m = o;
            }
            if (lane == 0) top[k] = (uint16_t)(0xFFFFu - (u32)(m & 0xFFFFu));
            if (q0 == m) q0 = 0; else if (q1 == m) q1 = 0;
            else if (q2 == m) q2 = 0; else if (q3 == m) q3 = 0;
        }
    }
    __syncthreads();
}

// ---- single-wave u32 top-50: zero barriers, non-destructive LDS reads ----
template <int NR>
__device__ void find32(const u32* cand, int nc, uint16_t* top, int lane) {
    u32 r[NR];
    #pragma unroll
    for (int j = 0; j < NR; ++j) {
        int idx = lane + j * 64;
        r[j] = (idx < nc) ? cand[idx] : 0u;
    }
    u32 mine = 0;
    for (int k = 0; k < KTOP; ++k) {
        u32 m = 0;
        #pragma unroll
        for (int j = 0; j < NR; ++j) m = r[j] > m ? r[j] : m;
        #pragma unroll
        for (int off = 32; off; off >>= 1) {
            u32 o = __shfl_xor(m, off);
            m = o > m ? o : m;
        }
        if (lane == k) mine = m;
        #pragma unroll
        for (int j = 0; j < NR; ++j) if (r[j] == m) r[j] = 0;
    }
    if (lane < KTOP) top[lane] = (uint16_t)(0xFFFFu - (mine & 0xFFFFu));
}

// ---- inline-asm load pair: issues 2x global_load_dwordx4, no compiler waits
#define ISSUE(RP, RQ, IDX) \
    asm volatile("global_load_dwordx4 %0, %2, off\n\t" \
                 "global_load_dwordx4 %1, %3, off" \
                 : "=&v"(RP), "=&v"(RQ) \
                 : "v"(vp4 + (IDX)), "v"(vq4 + (IDX)))

// counted wait: oldest pair complete, rest in flight; fence VALU hoisting
#define WAITV(N) do { \
    asm volatile("s_waitcnt vmcnt(" #N ")" ::: "memory"); \
    __builtin_amdgcn_sched_barrier(0); } while (0)

#define CONSUME(RP, RQ, G) do { \
    float _mp = fmaxf(fmaxf(RP.x, RP.y), fmaxf(RP.z, RP.w)); \
    float _mq = fmaxf(fmaxf(RQ.x, RQ.y), fmaxf(RQ.z, RQ.w)); \
    int _e = head + (((G) * NTHREADS + tid) << 2); \
    if (_mp >= tP) { \
        push32(candP, &s_c[C_CNTP], &s_c[C_OVF], RP.x, _e,     tP, tPb); \
        push32(candP, &s_c[C_CNTP], &s_c[C_OVF], RP.y, _e + 1, tP, tPb); \
        push32(candP, &s_c[C_CNTP], &s_c[C_OVF], RP.z, _e + 2, tP, tPb); \
        push32(candP, &s_c[C_CNTP], &s_c[C_OVF], RP.w, _e + 3, tP, tPb); \
    } \
    if (_mq >= tQ) { \
        push32(candQ, &s_c[C_CNTQ], &s_c[C_OVF], RQ.x, _e,     tQ, tQb); \
        push32(candQ, &s_c[C_CNTQ], &s_c[C_OVF], RQ.y, _e + 1, tQ, tQb); \
        push32(candQ, &s_c[C_CNTQ], &s_c[C_OVF], RQ.z, _e + 2, tQ, tQb); \
        push32(candQ, &s_c[C_CNTQ], &s_c[C_OVF], RQ.w, _e + 3, tQ, tQb); \
    } } while (0)

__global__ __launch_bounds__(NTHREADS, 4)
void topk_jsd_kernel(const float* __restrict__ p, const float* __restrict__ q,
                     float* __restrict__ out, int V)
{
    __shared__ u64 candRaw[CAP];                 // u32 views: P = lo 4KB, Q = hi 4KB
    __shared__ u64 s_merge[4 * KTOP];
    __shared__ float s_f[8];
    __shared__ u32 s_c[4];
    __shared__ uint16_t topP[KTOP];
    __shared__ uint16_t topQ[KTOP];
    __shared__ uint16_t s_union[2 * KTOP];
    __shared__ int s_nu;

    u32* candP = (u32*)candRaw;
    u32* candQ = ((u32*)candRaw) + CAP;

    const int row = blockIdx.x;
    const int tid = threadIdx.x;
    const int lane = tid & 63, w = tid >> 6;
    const float* prow = p + (size_t)row * (size_t)V;
    const float* qrow = q + (size_t)row * (size_t)V;

    // ---- sample phase: max of first 2048 elems ----
    int smp = V < 2048 ? V : 2048;
    float msP = 0.f, msQ = 0.f;
    for (int i = tid; i < smp; i += NTHREADS) {
        msP = fmaxf(msP, prow[i]);
        msQ = fmaxf(msQ, qrow[i]);
    }
    float MsP = block_max(msP, s_f, tid);
    float MsQ = block_max(msQ, s_f, tid);

    float eps0 = fminf(128.f / (float)V + 1.f / (float)smp, 0.5f);
    float tP = MsP * (1.f - eps0);
    float tQ = MsQ * (1.f - eps0);
    u32 tPb = __float_as_uint(tP), tQb = __float_as_uint(tQ);

    int misP = (int)(((uintptr_t)prow >> 2) & 3);
    int misQ = (int)(((uintptr_t)qrow >> 2) & 3);
    int headP = (4 - misP) & 3; if (headP > V) headP = V;
    int headQ = (4 - misQ) & 3; if (headQ > V) headQ = V;
    bool fast = (headP == headQ);

    int ncP = -1, ncQ = -1;
    u32 ovf = 1;

    if (fast) {
        int head = headP;
        if (tid == 0) { s_c[0] = 0; s_c[1] = 0; s_c[2] = 0; }
        __syncthreads();
        int nvec = (V - head) >> 2;
        const f4* vp4 = reinterpret_cast<const f4*>(prow + head);
        const f4* vq4 = reinterpret_cast<const f4*>(qrow + head);

        // head elements
        if (tid < head) {
            push32(candP, &s_c[C_CNTP], &s_c[C_OVF], prow[tid], tid, tP, tPb);
            push32(candQ, &s_c[C_CNTQ], &s_c[C_OVF], qrow[tid], tid, tQ, tQb);
        }

        // ---- inline-asm pipelined stream: 4-slot ring, 8 loads in flight ----
        int n4 = (nvec / NTHREADS) & ~3;   // per-thread groups, multiple of 4
        if (n4 >= 8) {
            f4 p0, p1, p2, p3, q0, q1, q2, q3;
            ISSUE(p0, q0, 0 * NTHREADS + tid);
            ISSUE(p1, q1, 1 * NTHREADS + tid);
            ISSUE(p2, q2, 2 * NTHREADS + tid);
            ISSUE(p3, q3, 3 * NTHREADS + tid);
            int gend = n4 - 4;             // multiple of 4
            for (int g = 0; g < gend; g += 4) {
                WAITV(6); CONSUME(p0, q0, g + 0); ISSUE(p0, q0, (g + 4) * NTHREADS + tid);
                WAITV(6); CONSUME(p1, q1, g + 1); ISSUE(p1, q1, (g + 5) * NTHREADS + tid);
                WAITV(6); CONSUME(p2, q2, g + 2); ISSUE(p2, q2, (g + 6) * NTHREADS + tid);
                WAITV(6); CONSUME(p3, q3, g + 3); ISSUE(p3, q3, (g + 7) * NTHREADS + tid);
            }
            WAITV(0);
            CONSUME(p0, q0, gend + 0);
            CONSUME(p1, q1, gend + 1);
            CONSUME(p2, q2, gend + 2);
            CONSUME(p3, q3, gend + 3);
        } else {
            n4 = 0;
        }

        // remaining float4s + scalar tail (per-element, validated path)
        for (int i = n4 * NTHREADS + tid; i < nvec; i += NTHREADS) {
            f4 a = vp4[i], b = vq4[i];
            int e = head + (i << 2);
            push32(candP, &s_c[C_CNTP], &s_c[C_OVF], a.x, e,     tP, tPb);
            push32(candP, &s_c[C_CNTP], &s_c[C_OVF], a.y, e + 1, tP, tPb);
            push32(candP, &s_c[C_CNTP], &s_c[C_OVF], a.z, e + 2, tP, tPb);
            push32(candP, &s_c[C_CNTP], &s_c[C_OVF], a.w, e + 3, tP, tPb);
            push32(candQ, &s_c[C_CNTQ], &s_c[C_OVF], b.x, e,     tQ, tQb);
            push32(candQ, &s_c[C_CNTQ], &s_c[C_OVF], b.y, e + 1, tQ, tQb);
            push32(candQ, &s_c[C_CNTQ], &s_c[C_OVF], b.z, e + 2, tQ, tQb);
            push32(candQ, &s_c[C_CNTQ], &s_c[C_OVF], b.w, e + 3, tQ, tQb);
        }
        for (int i = head + (nvec << 2) + tid; i < V; i += NTHREADS) {
            push32(candP, &s_c[C_CNTP], &s_c[C_OVF], prow[i], i, tP, tPb);
            push32(candQ, &s_c[C_CNTQ], &s_c[C_OVF], qrow[i], i, tQ, tQb);
        }
        __syncthreads();
        ncP = (int)s_c[C_CNTP];
        ncQ = (int)s_c[C_CNTQ];
        ovf = s_c[C_OVF];
        __syncthreads();
    }

    bool okP = fast && !ovf && ncP >= KTOP && ncP <= CAP;
    bool okQ = fast && !ovf && ncQ >= KTOP && ncQ <= CAP;

    // parallel single-wave extraction (non-destructive reads of cand LDS)
    if (okP && w == 0) {
        if (ncP <= 256) find32<4>(candP, ncP, topP, lane);
        else            find32<16>(candP, ncP, topP, lane);
    }
    if (okQ && w == 1) {
        if (ncQ <= 256) find32<4>(candQ, ncQ, topQ, lane);
        else            find32<16>(candQ, ncQ, topQ, lane);
    }

    // u64 fallback (validated path; overwrites candRaw)
    if (!okP) {
        float eps = eps0;
        int nc = collect_direct64(prow, V, MsP * (1.f - eps), candRaw, &s_c[C_GEN], tid);
        for (int a = 0; a < 10 && (nc < KTOP || nc > CAP); ++a) {
            eps = (nc > CAP) ? eps * 0.25f : fminf(eps * 4.f, 1.f);
            nc = collect_direct64(prow, V, MsP * (1.f - eps), candRaw, &s_c[C_GEN], tid);
        }
        if (nc > CAP) nc = CAP;
        find_topk64(candRaw, nc, topP, s_merge, tid);
    }
    if (!okQ) {
        float eps = eps0;
        int nc = collect_direct64(qrow, V, MsQ * (1.f - eps), candRaw, &s_c[C_GEN], tid);
        for (int a = 0; a < 10 && (nc < KTOP || nc > CAP); ++a) {
            eps = (nc > CAP) ? eps * 0.25f : fminf(eps * 4.f, 1.f);
            nc = collect_direct64(qrow, V, MsQ * (1.f - eps), candRaw, &s_c[C_GEN], tid);
        }
        if (nc > CAP) nc = CAP;
        find_topk64(candRaw, nc, topQ, s_merge, tid);
    }
    __syncthreads();

    // ---- union of index sets (wave 0) ----
    if (tid < KTOP) s_union[tid] = topP[tid];
    __syncthreads();
    if (tid < 64) {
        bool freshb = false; uint16_t qi = 0;
        if (tid < KTOP) {
            qi = topQ[tid]; freshb = true;
            for (int j = 0; j < KTOP; ++j) if (topP[j] == qi) freshb = false;
        }
        u64 mb = __ballot(freshb);
        int pos = __popcll(mb & ((1ull << tid) - 1ull));
        if (freshb) s_union[KTOP + pos] = qi;
        if (tid == 0) s_nu = KTOP + __popcll(mb);
    }
    __syncthreads();
    int nu = s_nu;

    // ---- gather union values (index clamp guards pathological fallbacks) ----
    float pv = 0.f, qv = 0.f;
    if (tid < nu) {
        int ui = s_union[tid]; ui = ui < V ? ui : V - 1;
        pv = prow[ui];
        qv = qrow[ui];
    }

    // ---- block-reduce masked sums ----
    float sp = pv, sq = qv;
    for (int off = 32; off; off >>= 1) { sp += __shfl_down(sp, off); sq += __shfl_down(sq, off); }
    if ((tid & 63) == 0) { s_f[w] = sp; s_f[4 + w] = sq; }
    __syncthreads();
    if (tid == 0) {
        float a = 0.f, b = 0.f;
        for (int ww = 0; ww < NTHREADS / 64; ++ww) { a += s_f[ww]; b += s_f[4 + ww]; }
        s_f[0] = a; s_f[4] = b;
    }
    __syncthreads();
    float sump = s_f[0], sumq = s_f[4];
    __syncthreads();

    // ---- JSD over union (identical formula to validated kernels) ----
    float term = 0.f;
    if (tid < nu) {
        float pn = pv / (sump + EPSV);
        float qn = qv / (sumq + EPSV);
        float mn = 0.5f * (pn + qn);
        float ps = pn + EPSV, qs = qn + EPSV, ms = mn + EPSV;
        term = 0.5f * (ps * logf(ps / ms) + qs * logf(qs / ms));
    }
    for (int off = 32; off; off >>= 1) term += __shfl_down(term, off);
    if ((tid & 63) == 0) s_f[w] = term;
    __syncthreads();
    if (tid == 0) {
        float a = 0.f;
        for (int ww = 0; ww < NTHREADS / 64; ++ww) a += s_f[ww];
        out[row] = a;
    }
}

extern "C" void kernel_launch(void* const* d_in, const int* in_sizes, int n_in,
                              void* d_out, int out_size, void* d_ws, size_t ws_size,
                              hipStream_t stream) {
    const float* p = (const float*)d_in[0];
    const float* q = (const float*)d_in[1];
    float* out = (float*)d_out;
    if (out_size <= 0) return;
    int N = out_size;            // B*S rows
    int V = in_sizes[0] / N;     // vocab size
    topk_jsd_kernel<<<dim3(N), dim3(NTHREADS), 0, stream>>>(p, q, out, V);
}